// Round 1
// baseline (172.124 us; speedup 1.0000x reference)
//
#include <hip/hip_runtime.h>

// RelationalGraphConvLayer: out[b,m,u] = relu(sum_e (adj[b,e]@feat[b]) @ ker[b,e])
// B=256, E=5, N=128, ATOM=64, UNITS=128, fp32 in/out, bf16 MFMA compute.

typedef __attribute__((ext_vector_type(8))) short s8v;  // 8 x bf16 (4 VGPRs) MFMA A/B frag
typedef __attribute__((ext_vector_type(4))) float f4v;  // MFMA C/D frag / float4 load

__device__ __forceinline__ short f2bf(float f) {
    // fp32 -> bf16 round-to-nearest-even (inputs finite; no NaN handling needed)
    unsigned u = __builtin_bit_cast(unsigned, f);
    u += 0x7FFFu + ((u >> 16) & 1u);
    return (short)(u >> 16);
}

__global__ __launch_bounds__(512, 2)
void rgc_kernel(const float* __restrict__ adj,
                const float* __restrict__ feat,
                const float* __restrict__ ker,
                float* __restrict__ out)
{
    // Row pads chosen so row stride is an odd multiple of 16 B -> b128 reads are
    // <=2-way bank aliased (free per m136).
    __shared__ __align__(16) short featT[64][136];    // featT[d][n] = feat[n][d]
    __shared__ __align__(16) short kerT[2][128][72];  // kerT[buf][u][d] = ker[d][u]
    __shared__ __align__(16) short YB[128][72];       // YB[m][d], wave-private rows

    const int b    = blockIdx.x;
    const int tid  = threadIdx.x;
    const int w    = tid >> 6;    // wave 0..7: owns output rows [16w, 16w+16)
    const int lane = tid & 63;
    const int c16  = lane & 15;
    const int quad = lane >> 4;

    const float* adjB  = adj  + (size_t)b * (5 * 128 * 128);
    const float* featB = feat + (size_t)b * (128 * 64);
    const float* kerB  = ker  + (size_t)b * (5 * 64 * 128);
    float*       outB  = out  + (size_t)b * (128 * 128);

    // ---- stage featT (bf16, transposed) once ----
    {
        f4v fv[4];
        #pragma unroll
        for (int i = 0; i < 4; ++i)
            fv[i] = *(const f4v*)(featB + (i * 512 + tid) * 4);
        #pragma unroll
        for (int i = 0; i < 4; ++i) {
            int g = i * 512 + tid;
            int n = g >> 4, d0 = (g & 15) << 2;
            #pragma unroll
            for (int j = 0; j < 4; ++j)
                featT[d0 + j][n] = f2bf(fv[i][j]);
        }
    }
    // ---- stage kerT[0] ----
    {
        f4v kv[4];
        #pragma unroll
        for (int i = 0; i < 4; ++i)
            kv[i] = *(const f4v*)(kerB + (i * 512 + tid) * 4);
        #pragma unroll
        for (int i = 0; i < 4; ++i) {
            int g = i * 512 + tid;
            int d = g >> 5, u0 = (g & 31) << 2;
            #pragma unroll
            for (int j = 0; j < 4; ++j)
                kerT[0][u0 + j][d] = f2bf(kv[i][j]);
        }
    }
    __syncthreads();

    f4v oacc[8] = {};  // out tiles (m16=w, u16=0..7)

    for (int e = 0; e < 5; ++e) {
        // ---- global loads: this wave's 16 adjacency rows (A-frags, no LDS) ----
        const float* ap = adjB + e * (128 * 128) + (16 * w + c16) * 128 + 8 * quad;
        f4v a0[4], a1[4];
        #pragma unroll
        for (int k16 = 0; k16 < 4; ++k16) {
            a0[k16] = *(const f4v*)(ap + 32 * k16);
            a1[k16] = *(const f4v*)(ap + 32 * k16 + 4);
        }
        // ---- global loads: next e's kernel (overlaps matmul1) ----
        f4v kv[4];
        const int en = e + 1;
        if (en < 5) {
            #pragma unroll
            for (int i = 0; i < 4; ++i)
                kv[i] = *(const f4v*)(kerB + en * (64 * 128) + (i * 512 + tid) * 4);
        }

        // ---- matmul1: Y[16w..16w+16) = adj_e @ feat  (M=16/wave, N=64, K=128) ----
        f4v yacc[4] = {};
        #pragma unroll
        for (int k16 = 0; k16 < 4; ++k16) {
            s8v af;
            #pragma unroll
            for (int j = 0; j < 4; ++j) af[j] = f2bf(a0[k16][j]);
            #pragma unroll
            for (int j = 0; j < 4; ++j) af[4 + j] = f2bf(a1[k16][j]);
            #pragma unroll
            for (int d16 = 0; d16 < 4; ++d16) {
                s8v bf = *(const s8v*)&featT[16 * d16 + c16][32 * k16 + 8 * quad];
                yacc[d16] = __builtin_amdgcn_mfma_f32_16x16x32_bf16(af, bf, yacc[d16], 0, 0, 0);
            }
        }

        // ---- Y -> LDS (C/D layout -> A-operand layout remap; wave-private rows) ----
        #pragma unroll
        for (int d16 = 0; d16 < 4; ++d16)
            #pragma unroll
            for (int r = 0; r < 4; ++r)
                YB[16 * w + 4 * quad + r][16 * d16 + c16] = f2bf(yacc[d16][r]);

        // ---- stage next kerT into the other buffer ----
        if (en < 5) {
            #pragma unroll
            for (int i = 0; i < 4; ++i) {
                int g = i * 512 + tid;
                int d = g >> 5, u0 = (g & 31) << 2;
                #pragma unroll
                for (int j = 0; j < 4; ++j)
                    kerT[en & 1][u0 + j][d] = f2bf(kv[i][j]);
            }
        }

        // ---- matmul2: OUT += Y @ ker_e  (M=16/wave, N=128, K=64) ----
        {
            const int buf = e & 1;
            s8v afr0 = *(const s8v*)&YB[16 * w + c16][8 * quad];
            s8v afr1 = *(const s8v*)&YB[16 * w + c16][32 + 8 * quad];
            #pragma unroll
            for (int u16 = 0; u16 < 8; ++u16) {
                s8v b0 = *(const s8v*)&kerT[buf][16 * u16 + c16][8 * quad];
                s8v b1 = *(const s8v*)&kerT[buf][16 * u16 + c16][32 + 8 * quad];
                oacc[u16] = __builtin_amdgcn_mfma_f32_16x16x32_bf16(afr0, b0, oacc[u16], 0, 0, 0);
                oacc[u16] = __builtin_amdgcn_mfma_f32_16x16x32_bf16(afr1, b1, oacc[u16], 0, 0, 0);
            }
        }
        __syncthreads();  // protects kerT double-buffer rotation only
    }

    // ---- epilogue: relu + store ----
    #pragma unroll
    for (int u16 = 0; u16 < 8; ++u16)
        #pragma unroll
        for (int r = 0; r < 4; ++r)
            outB[(16 * w + 4 * quad + r) * 128 + 16 * u16 + c16] = fmaxf(oacc[u16][r], 0.f);
}

extern "C" void kernel_launch(void* const* d_in, const int* in_sizes, int n_in,
                              void* d_out, int out_size, void* d_ws, size_t ws_size,
                              hipStream_t stream)
{
    const float* adj  = (const float*)d_in[0];
    const float* feat = (const float*)d_in[1];
    const float* ker  = (const float*)d_in[2];
    rgc_kernel<<<256, 512, 0, stream>>>(adj, feat, ker, (float*)d_out);
}